// Round 2
// baseline (2822.058 us; speedup 1.0000x reference)
//
#include <hip/hip_runtime.h>
#include <hip/hip_bf16.h>
#include <cstdint>
#include <cstddef>

#define TLEN 2048
#define NB 2
#define DMODEL 1024
#define NH 16
#define NDH 64
#define QT 32
#define JT 32

// ---------------------------------------------------------------------------
// Generic GEMM: C[m][n] = sum_k A[m][k] * W[n][k]   (A: MxK row-major,
// W: NxK row-major i.e. weight rows). 128x128 tile, 256 threads, 8x8 micro
// (split 4+4 to keep LDS reads 2-way max). Epilogue functor scatters C.
// ---------------------------------------------------------------------------

struct EpiQKV {
  float* q_s; float* k_s; float* v_s; const float* bias;
  __device__ void store(int m, int n, float val) const {
    int t = m >> 1, b = m & 1;               // m = t*B + b, B=2
    int which = n >> 10;
    int h = (n >> 6) & (NH - 1);
    int dh = n & (NDH - 1);
    size_t off = (((size_t)(b * NH + h)) * TLEN + t) * NDH + dh;
    if (which == 0)      q_s[off] = val + bias[(h << 6) | dh];
    else if (which == 1) k_s[off] = val;
    else                 v_s[off] = val;
  }
};

struct EpiRK {
  float* rk;
  __device__ void store(int m, int n, float val) const {
    int h = n >> 6, dh = n & 63;
    rk[((size_t)h * TLEN + m) * NDH + dh] = val;
  }
};

struct EpiOut {
  float* out;
  __device__ void store(int m, int n, float val) const {
    out[(size_t)m * DMODEL + n] = val;
  }
};

template <typename Epi>
__global__ __launch_bounds__(256) void gemm_nt(const float* __restrict__ A,
                                               const float* __restrict__ W,
                                               int K, Epi epi) {
  __shared__ float As[16][132];   // [k][row], padded
  __shared__ float Bs[16][132];
  const int tid = threadIdx.x;
  const int m0 = blockIdx.y * 128;
  const int n0 = blockIdx.x * 128;
  const int ty = tid >> 4, tx = tid & 15;

  float acc[8][8];
#pragma unroll
  for (int i = 0; i < 8; ++i)
#pragma unroll
    for (int j = 0; j < 8; ++j) acc[i][j] = 0.f;

  for (int k0 = 0; k0 < K; k0 += 16) {
#pragma unroll
    for (int it = 0; it < 2; ++it) {
      int idx = tid + it * 256;            // 512 float4 slots: 128 rows x 4
      int row = idx >> 2, c4 = (idx & 3) << 2;
      float4 va = *reinterpret_cast<const float4*>(A + (size_t)(m0 + row) * K + k0 + c4);
      As[c4 + 0][row] = va.x; As[c4 + 1][row] = va.y;
      As[c4 + 2][row] = va.z; As[c4 + 3][row] = va.w;
      float4 vb = *reinterpret_cast<const float4*>(W + (size_t)(n0 + row) * K + k0 + c4);
      Bs[c4 + 0][row] = vb.x; Bs[c4 + 1][row] = vb.y;
      Bs[c4 + 2][row] = vb.z; Bs[c4 + 3][row] = vb.w;
    }
    __syncthreads();
#pragma unroll
    for (int kk = 0; kk < 16; ++kk) {
      float4 a0 = *reinterpret_cast<const float4*>(&As[kk][ty * 4]);
      float4 a1 = *reinterpret_cast<const float4*>(&As[kk][64 + ty * 4]);
      float4 b0 = *reinterpret_cast<const float4*>(&Bs[kk][tx * 4]);
      float4 b1 = *reinterpret_cast<const float4*>(&Bs[kk][64 + tx * 4]);
      float av[8] = {a0.x, a0.y, a0.z, a0.w, a1.x, a1.y, a1.z, a1.w};
      float bv[8] = {b0.x, b0.y, b0.z, b0.w, b1.x, b1.y, b1.z, b1.w};
#pragma unroll
      for (int i = 0; i < 8; ++i)
#pragma unroll
        for (int j = 0; j < 8; ++j) acc[i][j] += av[i] * bv[j];
    }
    __syncthreads();
  }

#pragma unroll
  for (int i = 0; i < 8; ++i) {
    int m = m0 + ((i < 4) ? (ty * 4 + i) : (64 + ty * 4 + i - 4));
#pragma unroll
    for (int j = 0; j < 8; ++j) {
      int n = n0 + ((j < 4) ? (tx * 4 + j) : (64 + tx * 4 + j - 4));
      epi.store(m, n, acc[i][j]);
    }
  }
}

// ---------------------------------------------------------------------------
// Attention. Block = (b,h, 32 q-rows). Loops key chunks of 32.
// Score(q,j) = 0.125*(rq[q].k[j] + BD), BD per rel_shift:
//   j <= q   : rq[q]   . rk[2047-q+j]
//   j == q+1 : 0
//   j >= q+2 : rq[q+1] . rk[j-q-2]
// Both rk windows indexed by off = jl-ql+31 in [0,62].
// Writes unnormalized exp(score) (no max needed: |s| small) to prob, keeps
// row-sum l and PV accumulator; writes attn_vec = PV/l and l for rescale.
// ---------------------------------------------------------------------------

__device__ __forceinline__ int swzc(int d4, int row) {
  return ((d4 + (row >> 2)) & 15) << 2;   // bank-decorrelating column swizzle
}

__global__ __launch_bounds__(256) void attn_kernel(
    const float* __restrict__ q_s, const float* __restrict__ k_s,
    const float* __restrict__ v_s, const float* __restrict__ rk_s,
    const int* __restrict__ mask, float* __restrict__ prob,
    float* __restrict__ l_s, float* __restrict__ av_s) {
  const int bh = blockIdx.y;
  const int b = bh >> 4, h = bh & 15;
  const int q0 = blockIdx.x * QT;
  const int tid = threadIdx.x;

  __shared__ float rq[33][64];
  __shared__ float kt[32][64];
  __shared__ float vt[32][64];
  __shared__ float rk1[64][64];
  __shared__ float rk2[64][64];
  __shared__ float sl[32][33];
  __shared__ int mk[32];

  const float* qb  = q_s  + (size_t)bh * TLEN * NDH;
  const float* kb  = k_s  + (size_t)bh * TLEN * NDH;
  const float* vb  = v_s  + (size_t)bh * TLEN * NDH;
  const float* rkb = rk_s + (size_t)h  * TLEN * NDH;

  // stage rq rows q0..q0+32 (row 32 used for the j>=q+2 branch)
  for (int i = tid; i < 33 * 16; i += 256) {
    int row = i >> 4, c4 = (i & 15) << 2;
    int g = min(q0 + row, TLEN - 1);
    float4 v = *reinterpret_cast<const float4*>(qb + (size_t)g * NDH + c4);
    *reinterpret_cast<float4*>(&rq[row][swzc(c4 >> 2, row)]) = v;
  }

  const int ql = tid >> 3;            // q row 0..31
  const int jb = (tid & 7) << 2;      // 4 consecutive j per thread
  const int dc = (tid & 7) << 3;      // PV d-chunk (8 floats)
  const int qg = q0 + ql;
  float l_part = 0.f;
  float accv[8];
#pragma unroll
  for (int i = 0; i < 8; ++i) accv[i] = 0.f;

  for (int j0 = 0; j0 < TLEN; j0 += JT) {
    for (int i = tid; i < 32 * 16; i += 256) {
      int row = i >> 4, c4 = (i & 15) << 2;
      int cs = swzc(c4 >> 2, row);
      *reinterpret_cast<float4*>(&kt[row][cs]) =
          *reinterpret_cast<const float4*>(kb + (size_t)(j0 + row) * NDH + c4);
      *reinterpret_cast<float4*>(&vt[row][cs]) =
          *reinterpret_cast<const float4*>(vb + (size_t)(j0 + row) * NDH + c4);
    }
    for (int i = tid; i < 64 * 16; i += 256) {
      int row = i >> 4, c4 = (i & 15) << 2;
      int cs = swzc(c4 >> 2, row);
      int g1 = min(2016 - q0 + j0 + row, TLEN - 1);         // >= 0 always
      *reinterpret_cast<float4*>(&rk1[row][cs]) =
          *reinterpret_cast<const float4*>(rkb + (size_t)g1 * NDH + c4);
      int g2 = max(0, min(j0 - q0 - 33 + row, TLEN - 1));
      *reinterpret_cast<float4*>(&rk2[row][cs]) =
          *reinterpret_cast<const float4*>(rkb + (size_t)g2 * NDH + c4);
    }
    if (tid < JT) mk[tid] = mask[(size_t)(j0 + tid) * NB + b];
    __syncthreads();

    // ---- scores: 4 per thread (row ql, cols jb..jb+3) ----
    float ac[4] = {0.f, 0.f, 0.f, 0.f};
    float bd[4] = {0.f, 0.f, 0.f, 0.f};
    int off_s[4]; const float* rkrow[4]; bool up_s[4];
#pragma unroll
    for (int s = 0; s < 4; ++s) {
      int jl = jb + s;
      int jg = j0 + jl;
      int off = jl - ql + 31;
      bool br2 = (jg > qg + 1);
      off_s[s] = off; up_s[s] = br2;
      rkrow[s] = br2 ? &rk2[off][0] : &rk1[off][0];
    }
#pragma unroll
    for (int d4 = 0; d4 < 16; ++d4) {
      float4 a  = *reinterpret_cast<const float4*>(&rq[ql][swzc(d4, ql)]);
      float4 a1 = *reinterpret_cast<const float4*>(&rq[ql + 1][swzc(d4, ql + 1)]);
#pragma unroll
      for (int s = 0; s < 4; ++s) {
        int jl = jb + s;
        float4 kk = *reinterpret_cast<const float4*>(&kt[jl][swzc(d4, jl)]);
        ac[s] += a.x * kk.x + a.y * kk.y + a.z * kk.z + a.w * kk.w;
        float4 rv = *reinterpret_cast<const float4*>(rkrow[s] + swzc(d4, off_s[s]));
        float4 aa = up_s[s] ? a1 : a;
        bd[s] += aa.x * rv.x + aa.y * rv.y + aa.z * rv.z + aa.w * rv.w;
      }
    }
    float p[4];
#pragma unroll
    for (int s = 0; s < 4; ++s) {
      int jg = j0 + jb + s;
      float bdv = (jg == qg + 1) ? 0.f : bd[s];
      float sc = (ac[s] + bdv) * 0.125f;
      float pv = mk[jb + s] ? 0.f : __expf(sc);
      p[s] = pv;
      l_part += pv;
      sl[ql][jb + s] = pv;
    }
    *reinterpret_cast<float4*>(prob + ((size_t)bh * TLEN + qg) * TLEN + j0 + jb) =
        make_float4(p[0], p[1], p[2], p[3]);

    // ---- PV: sl row written by lanes of this same wave's 8-lane group ----
#pragma unroll 4
    for (int j = 0; j < JT; ++j) {
      float pj = sl[ql][j];
      float4 v0 = *reinterpret_cast<const float4*>(&vt[j][swzc(dc >> 2, j)]);
      float4 v1 = *reinterpret_cast<const float4*>(&vt[j][swzc((dc >> 2) + 1, j)]);
      accv[0] += pj * v0.x; accv[1] += pj * v0.y;
      accv[2] += pj * v0.z; accv[3] += pj * v0.w;
      accv[4] += pj * v1.x; accv[5] += pj * v1.y;
      accv[6] += pj * v1.z; accv[7] += pj * v1.w;
    }
    __syncthreads();
  }

#pragma unroll
  for (int o = 1; o < 8; o <<= 1) l_part += __shfl_xor(l_part, o);
  if ((tid & 7) == 0) l_s[(size_t)bh * TLEN + qg] = l_part;
  float inv = 1.0f / l_part;
  float4 o0 = make_float4(accv[0] * inv, accv[1] * inv, accv[2] * inv, accv[3] * inv);
  float4 o1 = make_float4(accv[4] * inv, accv[5] * inv, accv[6] * inv, accv[7] * inv);
  size_t ao = ((size_t)qg * NB + b) * DMODEL + h * NDH + dc;
  *reinterpret_cast<float4*>(av_s + ao) = o0;
  *reinterpret_cast<float4*>(av_s + ao + 4) = o1;
}

// prob *= 1/l, one block per (b,h,q) row
__global__ __launch_bounds__(256) void rescale_kernel(float* __restrict__ prob,
                                                      const float* __restrict__ l_s) {
  const int row = blockIdx.x;
  const float inv = 1.0f / l_s[row];
  float4* p = reinterpret_cast<float4*>(prob + (size_t)row * TLEN);
  int i = threadIdx.x;
  float4 v = p[i];
  v.x *= inv; v.y *= inv; v.z *= inv; v.w *= inv;
  p[i] = v;
  v = p[i + 256];
  v.x *= inv; v.y *= inv; v.z *= inv; v.w *= inv;
  p[i + 256] = v;
}

// ---------------------------------------------------------------------------

extern "C" void kernel_launch(void* const* d_in, const int* in_sizes, int n_in,
                              void* d_out, int out_size, void* d_ws, size_t ws_size,
                              hipStream_t stream) {
  const float* w      = (const float*)d_in[0];   // (T,B,D)
  const float* r      = (const float*)d_in[1];   // (T,D)
  const float* w_qkv  = (const float*)d_in[2];   // (3072,1024)
  const float* w_r    = (const float*)d_in[3];   // (1024,1024)
  const float* w_o    = (const float*)d_in[4];   // (1024,1024)
  const float* bias   = (const float*)d_in[5];   // (16,64)
  const int* mask     = (const int*)d_in[6];     // (T,B) bool -> int32

  float* out  = (float*)d_out;                          // T*B*D
  float* prob = out + (size_t)TLEN * NB * DMODEL;       // B*H*T*T

  float* ws = (float*)d_ws;
  const size_t SZ_QKV = (size_t)NB * NH * TLEN * NDH;   // 4194304
  float* q_s  = ws;
  float* k_s  = q_s + SZ_QKV;
  float* v_s  = k_s + SZ_QKV;
  float* rk_s = v_s + SZ_QKV;                           // NH*T*DH
  float* av_s = rk_s + (size_t)NH * TLEN * NDH;         // T*B*1024
  float* l_s  = av_s + (size_t)TLEN * NB * DMODEL;      // B*H*T

  EpiQKV e1{q_s, k_s, v_s, bias};
  gemm_nt<EpiQKV><<<dim3(3072 / 128, 4096 / 128), 256, 0, stream>>>(w, w_qkv, DMODEL, e1);
  EpiRK e2{rk_s};
  gemm_nt<EpiRK><<<dim3(1024 / 128, 2048 / 128), 256, 0, stream>>>(r, w_r, DMODEL, e2);
  attn_kernel<<<dim3(TLEN / QT, NB * NH), 256, 0, stream>>>(q_s, k_s, v_s, rk_s, mask,
                                                            prob, l_s, av_s);
  rescale_kernel<<<dim3(NB * NH * TLEN), 256, 0, stream>>>(prob, l_s);
  EpiOut e5{out};
  gemm_nt<EpiOut><<<dim3(1024 / 128, 4096 / 128), 256, 0, stream>>>(av_s, w_o, DMODEL, e5);
}

// Round 3
// 1173.277 us; speedup vs baseline: 2.4053x; 2.4053x over previous
//
#include <hip/hip_runtime.h>
#include <hip/hip_bf16.h>
#include <cstdint>
#include <cstddef>

#define TLEN 2048
#define NB 2
#define DMODEL 1024
#define NH 16
#define NDH 64

typedef short bf16x8 __attribute__((ext_vector_type(8)));
typedef float f32x16 __attribute__((ext_vector_type(16)));

__device__ __forceinline__ unsigned short f2bf(float f) {
  union { float f; unsigned int u; } x{f};
  unsigned int r = x.u + 0x7fff + ((x.u >> 16) & 1);   // RNE
  return (unsigned short)(r >> 16);
}
__device__ __forceinline__ unsigned int pk2(float lo, float hi) {
  return ((unsigned int)f2bf(hi) << 16) | (unsigned int)f2bf(lo);
}

// ---------------------------------------------------------------------------
// f32 GEMM (unchanged structure): C[m][n] = sum_k A[m][k] * W[n][k]
// ---------------------------------------------------------------------------

struct EpiQKV {   // -> bf16 q(+bias) [bh][t][d], k [bh][t][d], v TRANSPOSED [bh][d][t]
  unsigned short* qb; unsigned short* kb; unsigned short* vtb; const float* bias;
  __device__ void store(int m, int n, float val) const {
    int t = m >> 1, b = m & 1;
    int which = n >> 10;
    int h = (n >> 6) & (NH - 1);
    int dh = n & (NDH - 1);
    int bh = b * NH + h;
    if (which == 0)
      qb[((size_t)bh * TLEN + t) * NDH + dh] = f2bf(val + bias[(h << 6) | dh]);
    else if (which == 1)
      kb[((size_t)bh * TLEN + t) * NDH + dh] = f2bf(val);
    else
      vtb[((size_t)bh * NDH + dh) * TLEN + t] = f2bf(val);
  }
};

struct EpiRK {    // -> bf16 rk [h][t][d]
  unsigned short* rk;
  __device__ void store(int m, int n, float val) const {
    int h = n >> 6, dh = n & 63;
    rk[((size_t)h * TLEN + m) * NDH + dh] = f2bf(val);
  }
};

struct EpiOut {
  float* out;
  __device__ void store(int m, int n, float val) const {
    out[(size_t)m * DMODEL + n] = val;
  }
};

template <typename Epi>
__global__ __launch_bounds__(256) void gemm_nt(const float* __restrict__ A,
                                               const float* __restrict__ W,
                                               int K, Epi epi) {
  __shared__ float As[16][132];
  __shared__ float Bs[16][132];
  const int tid = threadIdx.x;
  const int m0 = blockIdx.y * 128;
  const int n0 = blockIdx.x * 128;
  const int ty = tid >> 4, tx = tid & 15;

  float acc[8][8];
#pragma unroll
  for (int i = 0; i < 8; ++i)
#pragma unroll
    for (int j = 0; j < 8; ++j) acc[i][j] = 0.f;

  for (int k0 = 0; k0 < K; k0 += 16) {
#pragma unroll
    for (int it = 0; it < 2; ++it) {
      int idx = tid + it * 256;
      int row = idx >> 2, c4 = (idx & 3) << 2;
      float4 va = *reinterpret_cast<const float4*>(A + (size_t)(m0 + row) * K + k0 + c4);
      As[c4 + 0][row] = va.x; As[c4 + 1][row] = va.y;
      As[c4 + 2][row] = va.z; As[c4 + 3][row] = va.w;
      float4 vb = *reinterpret_cast<const float4*>(W + (size_t)(n0 + row) * K + k0 + c4);
      Bs[c4 + 0][row] = vb.x; Bs[c4 + 1][row] = vb.y;
      Bs[c4 + 2][row] = vb.z; Bs[c4 + 3][row] = vb.w;
    }
    __syncthreads();
#pragma unroll
    for (int kk = 0; kk < 16; ++kk) {
      float4 a0 = *reinterpret_cast<const float4*>(&As[kk][ty * 4]);
      float4 a1 = *reinterpret_cast<const float4*>(&As[kk][64 + ty * 4]);
      float4 b0 = *reinterpret_cast<const float4*>(&Bs[kk][tx * 4]);
      float4 b1 = *reinterpret_cast<const float4*>(&Bs[kk][64 + tx * 4]);
      float av[8] = {a0.x, a0.y, a0.z, a0.w, a1.x, a1.y, a1.z, a1.w};
      float bv[8] = {b0.x, b0.y, b0.z, b0.w, b1.x, b1.y, b1.z, b1.w};
#pragma unroll
      for (int i = 0; i < 8; ++i)
#pragma unroll
        for (int j = 0; j < 8; ++j) acc[i][j] += av[i] * bv[j];
    }
    __syncthreads();
  }

#pragma unroll
  for (int i = 0; i < 8; ++i) {
    int m = m0 + ((i < 4) ? (ty * 4 + i) : (64 + ty * 4 + i - 4));
#pragma unroll
    for (int j = 0; j < 8; ++j) {
      int n = n0 + ((j < 4) ? (tx * 4 + j) : (64 + tx * 4 + j - 4));
      epi.store(m, n, acc[i][j]);
    }
  }
}

// ---------------------------------------------------------------------------
// MFMA attention. Block = (bh, 128 q rows); 4 waves, each owns 32 q rows.
// Per 32-j chunk (per wave):
//   S^T tile = mfma(A=K rows, B=Q frag)  (C: col=lane&31=q, row=j)
//   BD: 4 window tiles mfma(A=rk rows, B=Q or Qshift) -> LDS W[128][32],
//       diagonal gather at row (jl-ql+31) (+64 for branch-2).
//   p~ = exp(0.125*(AC+BD)) (0 if masked); f32 -> prob (unnormalized);
//   pack bf16 + half-swap -> PV A-frag; pacc += mfma(P, Vt).
// No __syncthreads anywhere (waves fully independent).
// ---------------------------------------------------------------------------

__global__ __launch_bounds__(256) void attn_mfma(
    const unsigned short* __restrict__ qb, const unsigned short* __restrict__ kb,
    const unsigned short* __restrict__ vtb, const unsigned short* __restrict__ rkb,
    const int* __restrict__ mask, float* __restrict__ prob,
    float* __restrict__ l_s, float* __restrict__ av_s) {
  __shared__ float W[4][128][32];

  const int bh = blockIdx.y;
  const int b = bh >> 4, h = bh & 15;
  const int wv = threadIdx.x >> 6;
  const int lane = threadIdx.x & 63;
  const int ql = lane & 31;
  const int hh = lane >> 5;
  const int q0 = blockIdx.x * 128 + wv * 32;
  const int qg = q0 + ql;

  const unsigned short* Qbh = qb + (size_t)bh * TLEN * NDH;
  const unsigned short* Kbh = kb + (size_t)bh * TLEN * NDH;
  const unsigned short* Vbh = vtb + (size_t)bh * NDH * TLEN;
  const unsigned short* Rh  = rkb + (size_t)h * TLEN * NDH;

  // loop-invariant Q / Q-shifted B-fragments (B[k=d][col=q], lane: q=ql, d-slice)
  bf16x8 Qf[4], Qs[4];
  {
    int r2 = min(qg + 1, TLEN - 1);
#pragma unroll
    for (int c = 0; c < 4; ++c) {
      Qf[c] = *(const bf16x8*)(Qbh + (size_t)qg * NDH + c * 16 + hh * 8);
      Qs[c] = *(const bf16x8*)(Qbh + (size_t)r2 * NDH + c * 16 + hh * 8);
    }
  }

  f32x16 pacc0, pacc1;
#pragma unroll
  for (int i = 0; i < 16; ++i) { pacc0[i] = 0.f; pacc1[i] = 0.f; }
  float l_acc = 0.f;

  for (int j0 = 0; j0 < TLEN; j0 += 32) {
    const int w1b = 2016 - q0 + j0;
    const int w2b = j0 - q0 - 33;

    // ---- 4 BD window tiles -> LDS ----
#pragma unroll
    for (int t = 0; t < 4; ++t) {
      int row = ((t < 2) ? w1b : w2b) + (t & 1) * 32 + ql;
      row = max(0, min(row, TLEN - 1));
      const unsigned short* src = Rh + (size_t)row * NDH + hh * 8;
      f32x16 facc;
#pragma unroll
      for (int i = 0; i < 16; ++i) facc[i] = 0.f;
#pragma unroll
      for (int c = 0; c < 4; ++c) {
        bf16x8 af = *(const bf16x8*)(src + c * 16);
        facc = __builtin_amdgcn_mfma_f32_32x32x16_bf16(af, (t < 2) ? Qf[c] : Qs[c],
                                                       facc, 0, 0, 0);
      }
      int rb = ((t >= 2) ? 64 : 0) + (t & 1) * 32;
#pragma unroll
      for (int r = 0; r < 16; ++r)
        W[wv][rb + (r & 3) + 8 * (r >> 2) + 4 * hh][ql] = facc[r];
    }

    // ---- AC tile (S^T) ----
    f32x16 cacc;
#pragma unroll
    for (int i = 0; i < 16; ++i) cacc[i] = 0.f;
    {
      const unsigned short* src = Kbh + (size_t)(j0 + ql) * NDH + hh * 8;
#pragma unroll
      for (int c = 0; c < 4; ++c) {
        bf16x8 af = *(const bf16x8*)(src + c * 16);
        cacc = __builtin_amdgcn_mfma_f32_32x32x16_bf16(af, Qf[c], cacc, 0, 0, 0);
      }
    }

    // ---- assemble scores, exp, prob store ----
    float p[16];
#pragma unroll
    for (int r = 0; r < 16; ++r) {
      int jrow = (r & 3) + 8 * (r >> 2) + 4 * hh;
      int jg = j0 + jrow;
      bool br2 = (jg > qg + 1);
      float bd = (jg == qg + 1) ? 0.f
                 : W[wv][jrow - ql + 31 + (br2 ? 64 : 0)][ql];
      float sc = (cacc[r] + bd) * 0.125f;
      float pv = mask[jg * NB + b] ? 0.f : __expf(sc);
      p[r] = pv;
      l_acc += pv;
    }
#pragma unroll
    for (int g = 0; g < 4; ++g) {
      float4 st = make_float4(p[4 * g + 0], p[4 * g + 1], p[4 * g + 2], p[4 * g + 3]);
      *reinterpret_cast<float4*>(prob + ((size_t)bh * TLEN + qg) * TLEN +
                                 j0 + 8 * g + 4 * hh) = st;
    }

    // ---- pack to PV A-frags (bf16) + half-swap; PV MFMA ----
#pragma unroll
    for (int kh = 0; kh < 2; ++kh) {
      unsigned int u0 = pk2(p[8 * kh + 0], p[8 * kh + 1]);
      unsigned int u1 = pk2(p[8 * kh + 2], p[8 * kh + 3]);
      unsigned int u2 = pk2(p[8 * kh + 4], p[8 * kh + 5]);
      unsigned int u3 = pk2(p[8 * kh + 6], p[8 * kh + 7]);
      unsigned int t0 = (unsigned int)__shfl_xor((int)u0, 32);
      unsigned int t1 = (unsigned int)__shfl_xor((int)u1, 32);
      unsigned int t2 = (unsigned int)__shfl_xor((int)u2, 32);
      unsigned int t3 = (unsigned int)__shfl_xor((int)u3, 32);
      unsigned int fr[4];
      fr[0] = hh ? t2 : u0;
      fr[1] = hh ? t3 : u1;
      fr[2] = hh ? u2 : t0;
      fr[3] = hh ? u3 : t1;
      bf16x8 pa = *reinterpret_cast<bf16x8*>(fr);
      const unsigned short* v0 = Vbh + (size_t)ql * TLEN + j0 + 16 * kh + 8 * hh;
      const unsigned short* v1 = Vbh + (size_t)(32 + ql) * TLEN + j0 + 16 * kh + 8 * hh;
      pacc0 = __builtin_amdgcn_mfma_f32_32x32x16_bf16(pa, *(const bf16x8*)v0, pacc0, 0, 0, 0);
      pacc1 = __builtin_amdgcn_mfma_f32_32x32x16_bf16(pa, *(const bf16x8*)v1, pacc1, 0, 0, 0);
    }
  }

  // ---- epilogue: l, normalize PV, store av ----
  float lt = l_acc + __shfl_xor(l_acc, 32);
  if (lane < 32) l_s[(size_t)bh * TLEN + qg] = lt;
  float inv = 1.0f / lt;
#pragma unroll
  for (int r = 0; r < 16; ++r) {
    int qrow = (r & 3) + 8 * (r >> 2) + 4 * hh;
    float iv = __shfl(inv, qrow);
    size_t aoff = ((size_t)(q0 + qrow) * NB + b) * DMODEL + h * NDH;
    av_s[aoff + ql] = pacc0[r] * iv;
    av_s[aoff + 32 + ql] = pacc1[r] * iv;
  }
}

// prob *= 1/l, one block per (b,h,q) row
__global__ __launch_bounds__(256) void rescale_kernel(float* __restrict__ prob,
                                                      const float* __restrict__ l_s) {
  const int row = blockIdx.x;
  const float inv = 1.0f / l_s[row];
  float4* p = reinterpret_cast<float4*>(prob + (size_t)row * TLEN);
  int i = threadIdx.x;
  float4 v = p[i];
  v.x *= inv; v.y *= inv; v.z *= inv; v.w *= inv;
  p[i] = v;
  v = p[i + 256];
  v.x *= inv; v.y *= inv; v.z *= inv; v.w *= inv;
  p[i + 256] = v;
}

// ---------------------------------------------------------------------------

extern "C" void kernel_launch(void* const* d_in, const int* in_sizes, int n_in,
                              void* d_out, int out_size, void* d_ws, size_t ws_size,
                              hipStream_t stream) {
  const float* w      = (const float*)d_in[0];   // (T,B,D)
  const float* r      = (const float*)d_in[1];   // (T,D)
  const float* w_qkv  = (const float*)d_in[2];   // (3072,1024)
  const float* w_r    = (const float*)d_in[3];   // (1024,1024)
  const float* w_o    = (const float*)d_in[4];   // (1024,1024)
  const float* bias   = (const float*)d_in[5];   // (16,64)
  const int* mask     = (const int*)d_in[6];     // (T,B) bool -> int32

  float* out  = (float*)d_out;
  float* prob = out + (size_t)TLEN * NB * DMODEL;

  const size_t SZ = (size_t)NB * NH * TLEN * NDH;        // 4M elems
  unsigned short* q_bf  = (unsigned short*)d_ws;
  unsigned short* k_bf  = q_bf + SZ;
  unsigned short* vt_bf = k_bf + SZ;
  unsigned short* rk_bf = vt_bf + SZ;                    // 2M elems
  float* av_s = (float*)(rk_bf + SZ / 2);
  float* l_s  = av_s + (size_t)TLEN * NB * DMODEL;

  EpiQKV e1{q_bf, k_bf, vt_bf, bias};
  gemm_nt<EpiQKV><<<dim3(3072 / 128, 4096 / 128), 256, 0, stream>>>(w, w_qkv, DMODEL, e1);
  EpiRK e2{rk_bf};
  gemm_nt<EpiRK><<<dim3(1024 / 128, 2048 / 128), 256, 0, stream>>>(r, w_r, DMODEL, e2);
  attn_mfma<<<dim3(TLEN / 128, NB * NH), 256, 0, stream>>>(q_bf, k_bf, vt_bf, rk_bf,
                                                           mask, prob, l_s, av_s);
  rescale_kernel<<<dim3(NB * NH * TLEN), 256, 0, stream>>>(prob, l_s);
  EpiOut e5{out};
  gemm_nt<EpiOut><<<dim3(1024 / 128, 4096 / 128), 256, 0, stream>>>(av_s, w_o, DMODEL, e5);
}

// Round 4
// 607.415 us; speedup vs baseline: 4.6460x; 1.9316x over previous
//
#include <hip/hip_runtime.h>
#include <hip/hip_bf16.h>
#include <cstdint>
#include <cstddef>

#define TLEN 2048
#define NB 2
#define DMODEL 1024
#define NH 16
#define NDH 64

typedef unsigned short ushortT;
typedef short bf16x8 __attribute__((ext_vector_type(8)));
typedef float f32x16 __attribute__((ext_vector_type(16)));

__device__ __forceinline__ ushortT f2bf(float f) {
  union { float f; unsigned int u; } x{f};
  unsigned int r = x.u + 0x7fff + ((x.u >> 16) & 1);   // RNE
  return (ushortT)(r >> 16);
}
__device__ __forceinline__ unsigned int pk2(float lo, float hi) {
  return ((unsigned int)f2bf(hi) << 16) | (unsigned int)f2bf(lo);
}
__device__ __forceinline__ float bf2f(ushortT u) {
  union { unsigned int u; float f; } x;
  x.u = ((unsigned int)u) << 16;
  return x.f;
}

__device__ __forceinline__ void gld_lds16(const void* g, void* l) {
  __builtin_amdgcn_global_load_lds(
      (const __attribute__((address_space(1))) unsigned int*)g,
      (__attribute__((address_space(3))) unsigned int*)l, 16, 0, 0);
}

// ---------------------------------------------------------------------------
// converts
// ---------------------------------------------------------------------------

__global__ __launch_bounds__(256) void cvt_bf16(const float* __restrict__ in,
                                                ushortT* __restrict__ out, int n4) {
  int i = blockIdx.x * 256 + threadIdx.x;
  if (i < n4) {
    float4 v = reinterpret_cast<const float4*>(in)[i];
    ushort4 o;
    o.x = f2bf(v.x); o.y = f2bf(v.y); o.z = f2bf(v.z); o.w = f2bf(v.w);
    reinterpret_cast<ushort4*>(out)[i] = o;
  }
}

__global__ __launch_bounds__(256) void cvt_mask(const int* __restrict__ mask,
                                                float* __restrict__ mfl) {
  int j = blockIdx.x * 256 + threadIdx.x;
  if (j < TLEN) {
    mfl[j]        = mask[j * NB]     ? 0.f : 1.f;
    mfl[TLEN + j] = mask[j * NB + 1] ? 0.f : 1.f;
  }
}

// ---------------------------------------------------------------------------
// bf16 MFMA GEMM: C[m][n] = sum_k A[m][k]*B[n][k], A:[M][K], B:[N][K] bf16.
// 128x128 tile, BK=64, 4 waves (2x2), per-wave 64x64 via 2x2 frags of
// 32x32x16. global_load_lds staging, LDS rows 128B with chunk^=(row&7)
// swizzle (pre-swizzled global source + swizzled ds_read, rule #21).
// ---------------------------------------------------------------------------

template <typename Epi>
__global__ __launch_bounds__(256) void gemm_bf16(const ushortT* __restrict__ A,
                                                 const ushortT* __restrict__ B,
                                                 int K, Epi epi) {
  __shared__ ushortT Al[128 * 64];
  __shared__ ushortT Bl[128 * 64];
  const int tid = threadIdx.x;
  const int lane = tid & 63;
  const int wv = tid >> 6;
  const int wm = wv >> 1, wn = wv & 1;
  const int m0 = blockIdx.y * 128;
  const int n0 = blockIdx.x * 128;
  const int r32 = lane & 31;
  const int hh = lane >> 5;

  f32x16 acc[2][2];
#pragma unroll
  for (int i = 0; i < 2; ++i)
#pragma unroll
    for (int j = 0; j < 2; ++j)
#pragma unroll
      for (int e = 0; e < 16; ++e) acc[i][j][e] = 0.f;

  for (int k0 = 0; k0 < K; k0 += 64) {
#pragma unroll
    for (int it = 0; it < 4; ++it) {
      int idx = it * 256 + tid;          // 1024 chunks of 16B
      int r = idx >> 3, c = idx & 7;
      int gcol = k0 + ((c ^ (r & 7)) << 3);
      gld_lds16(A + (size_t)(m0 + r) * K + gcol, Al + idx * 8);
      gld_lds16(B + (size_t)(n0 + r) * K + gcol, Bl + idx * 8);
    }
    asm volatile("s_waitcnt vmcnt(0)");
    __syncthreads();
#pragma unroll
    for (int kc = 0; kc < 4; ++kc) {
      int lc = kc * 2 + hh;              // logical 16B chunk in row
      bf16x8 af[2], bfr[2];
#pragma unroll
      for (int f = 0; f < 2; ++f) {
        int ar = wm * 64 + f * 32 + r32;
        af[f] = *(const bf16x8*)(Al + ar * 64 + ((lc ^ (ar & 7)) << 3));
        int br = wn * 64 + f * 32 + r32;
        bfr[f] = *(const bf16x8*)(Bl + br * 64 + ((lc ^ (br & 7)) << 3));
      }
#pragma unroll
      for (int i = 0; i < 2; ++i)
#pragma unroll
        for (int j = 0; j < 2; ++j)
          acc[i][j] = __builtin_amdgcn_mfma_f32_32x32x16_bf16(af[i], bfr[j],
                                                              acc[i][j], 0, 0, 0);
    }
    __syncthreads();
  }

#pragma unroll
  for (int i = 0; i < 2; ++i)
#pragma unroll
    for (int j = 0; j < 2; ++j)
#pragma unroll
      for (int rg = 0; rg < 16; ++rg) {
        int m = m0 + wm * 64 + i * 32 + (rg & 3) + 8 * (rg >> 2) + 4 * hh;
        int n = n0 + wn * 64 + j * 32 + r32;
        epi.store(m, n, acc[i][j][rg]);
      }
}

struct EpiQKV {   // q(+bias)->bf16 [bh][t][d], k->bf16 [bh][t][d], v->bf16 T [bh][d][t]
  ushortT* qb; ushortT* kb; ushortT* vtb; const float* bias;
  __device__ void store(int m, int n, float val) const {
    int t = m >> 1, b = m & 1;
    int which = n >> 10;
    int h = (n >> 6) & (NH - 1);
    int dh = n & (NDH - 1);
    int bh = b * NH + h;
    if (which == 0)
      qb[((size_t)bh * TLEN + t) * NDH + dh] = f2bf(val + bias[(h << 6) | dh]);
    else if (which == 1)
      kb[((size_t)bh * TLEN + t) * NDH + dh] = f2bf(val);
    else
      vtb[((size_t)bh * NDH + dh) * TLEN + t] = f2bf(val);
  }
};

struct EpiRK {
  ushortT* rk;
  __device__ void store(int m, int n, float val) const {
    int h = n >> 6, dh = n & 63;
    rk[((size_t)h * TLEN + m) * NDH + dh] = f2bf(val);
  }
};

struct EpiOut {
  float* out;
  __device__ void store(int m, int n, float val) const {
    out[(size_t)m * DMODEL + n] = val;
  }
};

// ---------------------------------------------------------------------------
// MFMA attention. Block = (bh, 128 q rows); 4 waves x 32 q rows each.
// Per 32-j chunk only 2 rel-shift window tiles are live:
//   j0 <  q0 : window1 rows [0,64)    (all pairs have jg <= qg+1)
//   j0 == q0 : window1 rows [0,32) + window2 rows [32,64)
//   j0 >  q0 : window2 rows [0,64)    (all pairs have jg >= qg+1)
// (jg == qg+1 diagonal is exactly 0 and skipped.)
// p~ = mfl * exp(0.125*(AC+BD)) stored bf16 into the upper half of each
// f32 prob row's 8KB slot; PV accumulated via MFMA; av stored bf16.
// ---------------------------------------------------------------------------

__global__ __launch_bounds__(256) void attn_mfma(
    const ushortT* __restrict__ qb, const ushortT* __restrict__ kb,
    const ushortT* __restrict__ vtb, const ushortT* __restrict__ rkb,
    const float* __restrict__ mfl, float* __restrict__ prob,
    float* __restrict__ l_s, ushortT* __restrict__ av_bf) {
  __shared__ float W[4][64][32];

  const int bh = blockIdx.y;
  const int b = bh >> 4, h = bh & 15;
  const int wv = threadIdx.x >> 6;
  const int lane = threadIdx.x & 63;
  const int ql = lane & 31;
  const int hh = lane >> 5;
  const int q0 = blockIdx.x * 128 + wv * 32;
  const int qg = q0 + ql;

  const ushortT* Qbh = qb + (size_t)bh * TLEN * NDH;
  const ushortT* Kbh = kb + (size_t)bh * TLEN * NDH;
  const ushortT* Vbh = vtb + (size_t)bh * NDH * TLEN;
  const ushortT* Rh  = rkb + (size_t)h * TLEN * NDH;
  const float* mflb  = mfl + (size_t)b * TLEN;

  bf16x8 Qf[4], Qs[4];
  {
    int r2 = min(qg + 1, TLEN - 1);
#pragma unroll
    for (int c = 0; c < 4; ++c) {
      Qf[c] = *(const bf16x8*)(Qbh + (size_t)qg * NDH + c * 16 + hh * 8);
      Qs[c] = *(const bf16x8*)(Qbh + (size_t)r2 * NDH + c * 16 + hh * 8);
    }
  }

  f32x16 pacc0, pacc1;
#pragma unroll
  for (int i = 0; i < 16; ++i) { pacc0[i] = 0.f; pacc1[i] = 0.f; }
  float l_acc = 0.f;

  ushortT* pbrow = (ushortT*)prob + ((size_t)bh * TLEN + qg) * 4096 + 2048;

  for (int j0 = 0; j0 < TLEN; j0 += 32) {
    const int w1b = 2016 - q0 + j0;
    const int w2b = j0 - q0 - 33;
    const int base0 = (j0 <= q0) ? w1b : w2b;
    const int base1 = ((j0 < q0) ? w1b : w2b) + 32;
    const bool t0w1 = (j0 <= q0);
    const bool t1w1 = (j0 < q0);

#pragma unroll
    for (int t = 0; t < 2; ++t) {
      int row = (t ? base1 : base0) + ql;
      row = max(0, min(row, TLEN - 1));
      const ushortT* src = Rh + (size_t)row * NDH + hh * 8;
      bool useQf = t ? t1w1 : t0w1;
      f32x16 facc;
#pragma unroll
      for (int i = 0; i < 16; ++i) facc[i] = 0.f;
#pragma unroll
      for (int c = 0; c < 4; ++c) {
        bf16x8 af = *(const bf16x8*)(src + c * 16);
        facc = __builtin_amdgcn_mfma_f32_32x32x16_bf16(af, useQf ? Qf[c] : Qs[c],
                                                       facc, 0, 0, 0);
      }
#pragma unroll
      for (int r = 0; r < 16; ++r)
        W[wv][t * 32 + (r & 3) + 8 * (r >> 2) + 4 * hh][ql] = facc[r];
    }

    // AC tile (S^T)
    f32x16 cacc;
#pragma unroll
    for (int i = 0; i < 16; ++i) cacc[i] = 0.f;
    {
      const ushortT* src = Kbh + (size_t)(j0 + ql) * NDH + hh * 8;
#pragma unroll
      for (int c = 0; c < 4; ++c) {
        bf16x8 af = *(const bf16x8*)(src + c * 16);
        cacc = __builtin_amdgcn_mfma_f32_32x32x16_bf16(af, Qf[c], cacc, 0, 0, 0);
      }
    }

    float4 mf4[4];
#pragma unroll
    for (int g = 0; g < 4; ++g)
      mf4[g] = *(const float4*)(mflb + j0 + 8 * g + 4 * hh);

    float p[16];
#pragma unroll
    for (int r = 0; r < 16; ++r) {
      int jrow = (r & 3) + 8 * (r >> 2) + 4 * hh;
      int jg = j0 + jrow;
      float bd = (jg == qg + 1) ? 0.f : W[wv][jrow - ql + 31][ql];
      float sc = (cacc[r] + bd) * 0.125f;
      float mv = (&mf4[r >> 2].x)[r & 3];
      float pv = mv * __expf(sc);
      p[r] = pv;
      l_acc += pv;
    }

    // p~ bf16 store (4 x 8B)
#pragma unroll
    for (int g = 0; g < 4; ++g) {
      uint2 st;
      st.x = pk2(p[4 * g + 0], p[4 * g + 1]);
      st.y = pk2(p[4 * g + 2], p[4 * g + 3]);
      *reinterpret_cast<uint2*>(pbrow + j0 + 8 * g + 4 * hh) = st;
    }

    // PV
#pragma unroll
    for (int kh = 0; kh < 2; ++kh) {
      unsigned int u0 = pk2(p[8 * kh + 0], p[8 * kh + 1]);
      unsigned int u1 = pk2(p[8 * kh + 2], p[8 * kh + 3]);
      unsigned int u2 = pk2(p[8 * kh + 4], p[8 * kh + 5]);
      unsigned int u3 = pk2(p[8 * kh + 6], p[8 * kh + 7]);
      unsigned int t0 = (unsigned int)__shfl_xor((int)u0, 32);
      unsigned int t1 = (unsigned int)__shfl_xor((int)u1, 32);
      unsigned int t2 = (unsigned int)__shfl_xor((int)u2, 32);
      unsigned int t3 = (unsigned int)__shfl_xor((int)u3, 32);
      unsigned int fr[4];
      fr[0] = hh ? t2 : u0;
      fr[1] = hh ? t3 : u1;
      fr[2] = hh ? u2 : t0;
      fr[3] = hh ? u3 : t1;
      bf16x8 pa = *reinterpret_cast<bf16x8*>(fr);
      const ushortT* v0 = Vbh + (size_t)ql * TLEN + j0 + 16 * kh + 8 * hh;
      const ushortT* v1 = Vbh + (size_t)(32 + ql) * TLEN + j0 + 16 * kh + 8 * hh;
      pacc0 = __builtin_amdgcn_mfma_f32_32x32x16_bf16(pa, *(const bf16x8*)v0, pacc0, 0, 0, 0);
      pacc1 = __builtin_amdgcn_mfma_f32_32x32x16_bf16(pa, *(const bf16x8*)v1, pacc1, 0, 0, 0);
    }
  }

  float lt = l_acc + __shfl_xor(l_acc, 32);
  if (lane < 32) l_s[(size_t)bh * TLEN + qg] = lt;
  float inv = 1.0f / lt;
#pragma unroll
  for (int r = 0; r < 16; ++r) {
    int qrow = (r & 3) + 8 * (r >> 2) + 4 * hh;
    float iv = __shfl(inv, qrow);
    size_t aoff = ((size_t)(q0 + qrow) * NB + b) * DMODEL + h * NDH;
    av_bf[aoff + ql] = f2bf(pacc0[r] * iv);
    av_bf[aoff + 32 + ql] = f2bf(pacc1[r] * iv);
  }
}

// ---------------------------------------------------------------------------
// prob row: read bf16 p~ from upper half of the row's 8KB slot, barrier,
// write f32 p~/l over the whole slot. Row-local overlap only.
// ---------------------------------------------------------------------------

__global__ __launch_bounds__(256) void rescale_kernel(float* __restrict__ prob,
                                                      const float* __restrict__ l_s) {
  const int row = blockIdx.x;
  const float inv = 1.0f / l_s[row];
  const int t = threadIdx.x;
  const ushortT* src = (const ushortT*)prob + (size_t)row * 4096 + 2048 + t * 8;
  uint4 u = *reinterpret_cast<const uint4*>(src);
  __syncthreads();
  float o[8];
  o[0] = bf2f((ushortT)(u.x & 0xffff)) * inv;
  o[1] = bf2f((ushortT)(u.x >> 16)) * inv;
  o[2] = bf2f((ushortT)(u.y & 0xffff)) * inv;
  o[3] = bf2f((ushortT)(u.y >> 16)) * inv;
  o[4] = bf2f((ushortT)(u.z & 0xffff)) * inv;
  o[5] = bf2f((ushortT)(u.z >> 16)) * inv;
  o[6] = bf2f((ushortT)(u.w & 0xffff)) * inv;
  o[7] = bf2f((ushortT)(u.w >> 16)) * inv;
  float4* dst = reinterpret_cast<float4*>(prob + (size_t)row * 2048 + t * 8);
  dst[0] = make_float4(o[0], o[1], o[2], o[3]);
  dst[1] = make_float4(o[4], o[5], o[6], o[7]);
}

// ---------------------------------------------------------------------------

extern "C" void kernel_launch(void* const* d_in, const int* in_sizes, int n_in,
                              void* d_out, int out_size, void* d_ws, size_t ws_size,
                              hipStream_t stream) {
  const float* w      = (const float*)d_in[0];   // (T,B,D)
  const float* r      = (const float*)d_in[1];   // (T,D)
  const float* w_qkv  = (const float*)d_in[2];   // (3072,1024)
  const float* w_r    = (const float*)d_in[3];   // (1024,1024)
  const float* w_o    = (const float*)d_in[4];   // (1024,1024)
  const float* bias   = (const float*)d_in[5];   // (16,64)
  const int* mask     = (const int*)d_in[6];     // (T,B) int32

  float* out  = (float*)d_out;
  float* prob = out + (size_t)TLEN * NB * DMODEL;

  const size_t SZ = (size_t)NB * NH * TLEN * NDH;        // 4194304
  ushortT* w_bf    = (ushortT*)d_ws;
  ushortT* wqkv_bf = w_bf + (size_t)4096 * 1024;
  ushortT* r_bf    = wqkv_bf + (size_t)3072 * 1024;
  ushortT* wr_bf   = r_bf + (size_t)2048 * 1024;
  ushortT* wo_bf   = wr_bf + (size_t)1024 * 1024;
  ushortT* q_bf    = wo_bf + (size_t)1024 * 1024;
  ushortT* k_bf    = q_bf + SZ;
  ushortT* vt_bf   = k_bf + SZ;
  ushortT* rk_bf   = vt_bf + SZ;
  ushortT* av_bf   = rk_bf + SZ / 2;
  float* l_s       = (float*)(av_bf + SZ);
  float* mfl       = l_s + (size_t)NB * NH * TLEN;

  cvt_bf16<<<4096, 256, 0, stream>>>(w, w_bf, 4096 * 1024 / 4);
  cvt_bf16<<<3072, 256, 0, stream>>>(w_qkv, wqkv_bf, 3072 * 1024 / 4);
  cvt_bf16<<<2048, 256, 0, stream>>>(r, r_bf, 2048 * 1024 / 4);
  cvt_bf16<<<1024, 256, 0, stream>>>(w_r, wr_bf, 1024 * 1024 / 4);
  cvt_bf16<<<1024, 256, 0, stream>>>(w_o, wo_bf, 1024 * 1024 / 4);
  cvt_mask<<<8, 256, 0, stream>>>(mask, mfl);

  EpiQKV e1{q_bf, k_bf, vt_bf, bias};
  gemm_bf16<EpiQKV><<<dim3(3072 / 128, 4096 / 128), 256, 0, stream>>>(w_bf, wqkv_bf, DMODEL, e1);
  EpiRK e2{rk_bf};
  gemm_bf16<EpiRK><<<dim3(1024 / 128, 2048 / 128), 256, 0, stream>>>(r_bf, wr_bf, DMODEL, e2);

  attn_mfma<<<dim3(TLEN / 128, NB * NH), 256, 0, stream>>>(q_bf, k_bf, vt_bf, rk_bf,
                                                           mfl, prob, l_s, av_bf);
  rescale_kernel<<<dim3(NB * NH * TLEN), 256, 0, stream>>>(prob, l_s);

  EpiOut e5{out};
  gemm_bf16<EpiOut><<<dim3(1024 / 128, 4096 / 128), 256, 0, stream>>>(av_bf, wo_bf, DMODEL, e5);
}